// Round 2
// baseline (604.007 us; speedup 1.0000x reference)
//
#include <hip/hip_runtime.h>
#include <cstdint>
#include <cstddef>

#define NB 8
#define NN 65536
#define GG 64
#define GG3 (GG*GG*GG)
#define NW (GG3/32)          // 8192 mask words per batch
#define EPSC 1e-3f

// rank of active site lin within batch, or -1 if inactive.
__device__ __forceinline__ int site_rank(const uint32_t* __restrict__ mb,
                                         const int* __restrict__ wb, int lin) {
    uint32_t w = mb[lin >> 5];
    uint32_t bit = 1u << (lin & 31);
    if (!(w & bit)) return -1;
    return wb[lin >> 5] + __popc(w & (bit - 1u));
}

// ---------------------------------------------------------------------------
// K1: occupancy bitmask (mask pre-memset to 0)
// ---------------------------------------------------------------------------
__global__ __launch_bounds__(256) void build_mask_kernel(
    const int* __restrict__ xyz, const int* __restrict__ nvv,
    uint32_t* __restrict__ mask)
{
    int b = blockIdx.y;
    int n = blockIdx.x * 256 + threadIdx.x;
    if (n < nvv[b]) {
        const int* cp = xyz + ((size_t)b * NN + n) * 3;
        int lin = cp[0] * (GG * GG) + cp[1] * GG + cp[2];
        atomicOr(&mask[b * NW + (lin >> 5)], 1u << (lin & 31));
    }
}

// ---------------------------------------------------------------------------
// K2: exclusive prefix sum of popcounts over the 8192 words of one batch
// ---------------------------------------------------------------------------
__global__ __launch_bounds__(256) void scan_mask_kernel(
    const uint32_t* __restrict__ mask, int* __restrict__ wbase)
{
    int b = blockIdx.x;
    const uint32_t* mb = mask + (size_t)b * NW;
    int* wb = wbase + (size_t)b * NW;
    int t = threadIdx.x;

    int cnts[32];
    int local = 0;
    #pragma unroll
    for (int i = 0; i < 32; i++) { cnts[i] = __popc(mb[t * 32 + i]); local += cnts[i]; }

    __shared__ int sc[256];
    sc[t] = local;
    __syncthreads();
    for (int off = 1; off < 256; off <<= 1) {
        int v = (t >= off) ? sc[t - off] : 0;
        __syncthreads();
        sc[t] += v;
        __syncthreads();
    }
    int base = sc[t] - local;   // exclusive
    #pragma unroll
    for (int i = 0; i < 32; i++) { wb[t * 32 + i] = base; base += cnts[i]; }
}

// ---------------------------------------------------------------------------
// K3: build permutation + gather feats into rank-sorted order
// ---------------------------------------------------------------------------
__global__ __launch_bounds__(256) void perm_gather_kernel(
    const int* __restrict__ xyz, const int* __restrict__ nvv,
    const uint32_t* __restrict__ mask, const int* __restrict__ wbase,
    const float* __restrict__ feats,
    int* __restrict__ s2o, int* __restrict__ slin, float* __restrict__ sfeats)
{
    int b = blockIdx.y;
    int n = blockIdx.x * 256 + threadIdx.x;
    if (n >= nvv[b]) return;
    const int* cp = xyz + ((size_t)b * NN + n) * 3;
    int lin = cp[0] * (GG * GG) + cp[1] * GG + cp[2];
    int r = site_rank(mask + (size_t)b * NW, wbase + (size_t)b * NW, lin);
    s2o[b * NN + r] = n;
    slin[b * NN + r] = lin;
    const float4* fp = (const float4*)(feats + ((size_t)b * NN + n) * 16);
    float4* op = (float4*)(sfeats + ((size_t)b * NN + r) * 16);
    op[0] = fp[0]; op[1] = fp[1]; op[2] = fp[2]; op[3] = fp[3];
}

// ---------------------------------------------------------------------------
// K4/K6: sparse conv over rank-sorted sites.
//   FUSE_BN: apply y=relu(x*sc+bias) (from sbin) to each gathered input row
//   SCATTER: write output to original row order via s2o, else sorted order
// Fuses ones-conv normalizer and BN partial-stat reduction.
// ---------------------------------------------------------------------------
template<bool FUSE_BN, bool SCATTER>
__global__ __launch_bounds__(256) void conv_sorted_kernel(
    const float* __restrict__ sfeats,    // (B,N,16) rank-sorted input
    const int*   __restrict__ slin,      // (B,N) rank -> lin
    const int*   __restrict__ nvv,
    const uint32_t* __restrict__ mask,
    const int*   __restrict__ wbase,
    const float* __restrict__ w,         // (27,16,16)
    const float* __restrict__ nw,        // (27,)
    const float* __restrict__ sbin,      // scale/bias of previous BN (or null)
    const int*   __restrict__ s2o,       // rank -> original row (or null)
    float*       __restrict__ outbuf,
    float*       __restrict__ partials)
{
    int b = blockIdx.y;
    int r = blockIdx.x * 256 + threadIdx.x;
    int cnt = nvv[b];

    float t[16];
    #pragma unroll
    for (int o = 0; o < 16; o++) t[o] = 0.f;

    if (r < cnt) {
        int lin = slin[b * NN + r];
        int x = lin >> 12, y = (lin >> 6) & 63, z = lin & 63;
        const uint32_t* mb = mask + (size_t)b * NW;
        const int* wb = wbase + (size_t)b * NW;
        const float* fb = sfeats + (size_t)b * NN * 16;

        float sc[16], bi[16];
        if (FUSE_BN) {
            #pragma unroll
            for (int c = 0; c < 16; c++) { sc[c] = sbin[c]; bi[c] = sbin[16 + c]; }
        }

        float acc[16];
        #pragma unroll
        for (int o = 0; o < 16; o++) acc[o] = 0.f;
        float normc = 0.f;

        #pragma unroll 1
        for (int off = 0; off < 27; off++) {
            int dx = off / 9 - 1, dy = (off / 3) % 3 - 1, dz = off % 3 - 1;
            int nx = x + dx, ny = y + dy, nz = z + dz;
            int j = -1;
            if ((unsigned)nx < GG && (unsigned)ny < GG && (unsigned)nz < GG)
                j = site_rank(mb, wb, nx * (GG * GG) + ny * GG + nz);
            if (j >= 0) {
                normc += nw[off];
                const float4* fp = (const float4*)(fb + (size_t)j * 16);
                float4 f0 = fp[0], f1 = fp[1], f2 = fp[2], f3 = fp[3];
                float f[16] = {f0.x, f0.y, f0.z, f0.w, f1.x, f1.y, f1.z, f1.w,
                               f2.x, f2.y, f2.z, f2.w, f3.x, f3.y, f3.z, f3.w};
                if (FUSE_BN) {
                    #pragma unroll
                    for (int c = 0; c < 16; c++)
                        f[c] = fmaxf(fmaf(f[c], sc[c], bi[c]), 0.f);
                }
                const float* wp = w + off * 256;   // wave-uniform -> s_load
                #pragma unroll
                for (int c = 0; c < 16; c++) {
                    #pragma unroll
                    for (int o = 0; o < 16; o++)
                        acc[o] = fmaf(f[c], wp[c * 16 + o], acc[o]);
                }
            }
        }

        float rr = 1.f / (1.f + fabsf(normc));
        #pragma unroll
        for (int o = 0; o < 16; o++) t[o] = acc[o] * rr;

        size_t orow = (size_t)b * NN + (SCATTER ? (size_t)s2o[b * NN + r] : (size_t)r);
        float4* op = (float4*)(outbuf + orow * 16);
        op[0] = make_float4(t[0],  t[1],  t[2],  t[3]);
        op[1] = make_float4(t[4],  t[5],  t[6],  t[7]);
        op[2] = make_float4(t[8],  t[9],  t[10], t[11]);
        op[3] = make_float4(t[12], t[13], t[14], t[15]);
    }

    // --- BN partial stats: 32 values (sum[0:16], sumsq[16:32]) ---
    __shared__ float red[4][32];
    int lane = threadIdx.x & 63;
    int wv = threadIdx.x >> 6;
    #pragma unroll
    for (int s = 0; s < 32; s++) {
        float v = (s < 16) ? t[s] : t[s - 16] * t[s - 16];
        v += __shfl_down(v, 32, 64);
        v += __shfl_down(v, 16, 64);
        v += __shfl_down(v, 8, 64);
        v += __shfl_down(v, 4, 64);
        v += __shfl_down(v, 2, 64);
        v += __shfl_down(v, 1, 64);
        if (lane == 0) red[wv][s] = v;
    }
    __syncthreads();
    if (threadIdx.x < 32) {
        float v = red[0][threadIdx.x] + red[1][threadIdx.x] +
                  red[2][threadIdx.x] + red[3][threadIdx.x];
        partials[((size_t)blockIdx.y * gridDim.x + blockIdx.x) * 32 + threadIdx.x] = v;
    }
}

// ---------------------------------------------------------------------------
// K5/K7: reduce partials -> per-channel scale/bias (single block)
// ---------------------------------------------------------------------------
__global__ __launch_bounds__(256) void finalize_kernel(
    const float* __restrict__ partials, int nparts,
    const int*   __restrict__ nvv,
    const float* __restrict__ gamma, const float* __restrict__ beta,
    float*       __restrict__ sb)     // sb[0:16]=scale, sb[16:32]=bias
{
    __shared__ float red[8][32];
    __shared__ float tot[32];
    int s = threadIdx.x & 31;
    int ch = threadIdx.x >> 5;
    float v = 0.f;
    for (int r = ch; r < nparts; r += 8)
        v += partials[(size_t)r * 32 + s];
    red[ch][s] = v;
    __syncthreads();
    if (threadIdx.x < 32) {
        float x = 0.f;
        #pragma unroll
        for (int k = 0; k < 8; k++) x += red[k][threadIdx.x];
        tot[threadIdx.x] = x;
    }
    __syncthreads();
    if (threadIdx.x < 16) {
        float cnt = 0.f;
        #pragma unroll
        for (int b = 0; b < NB; b++) cnt += (float)nvv[b];
        float mean = tot[threadIdx.x] / cnt;
        float var  = tot[16 + threadIdx.x] / cnt - mean * mean;
        var = fmaxf(var, 0.f);
        float scv = gamma[threadIdx.x] * rsqrtf(var + EPSC);
        sb[threadIdx.x]      = scv;
        sb[16 + threadIdx.x] = beta[threadIdx.x] - mean * scv;
    }
}

// ---------------------------------------------------------------------------
// K8: final y = relu(x*scale + bias) for valid rows, zeros elsewhere
// ---------------------------------------------------------------------------
__global__ __launch_bounds__(256) void bnrelu_kernel(
    const float* __restrict__ in, const float* __restrict__ sb,
    const int* __restrict__ nvv, float* __restrict__ out)
{
    size_t i = (size_t)blockIdx.x * 256 + threadIdx.x;   // one float4
    int row = (int)(i >> 2);          // b*N + n
    int b = row >> 16;                // N == 65536
    int n = row & (NN - 1);
    int o = ((int)i & 3) * 4;
    float4 y = make_float4(0.f, 0.f, 0.f, 0.f);
    if (n < nvv[b]) {
        float4 x = ((const float4*)in)[i];
        y.x = fmaxf(fmaf(x.x, sb[o + 0], sb[16 + o + 0]), 0.f);
        y.y = fmaxf(fmaf(x.y, sb[o + 1], sb[16 + o + 1]), 0.f);
        y.z = fmaxf(fmaf(x.z, sb[o + 2], sb[16 + o + 2]), 0.f);
        y.w = fmaxf(fmaf(x.w, sb[o + 3], sb[16 + o + 3]), 0.f);
    }
    ((float4*)out)[i] = y;
}

// ---------------------------------------------------------------------------
extern "C" void kernel_launch(void* const* d_in, const int* in_sizes, int n_in,
                              void* d_out, int out_size, void* d_ws, size_t ws_size,
                              hipStream_t stream)
{
    const float* feats  = (const float*)d_in[0];
    const int*   xyz    = (const int*)d_in[1];
    const int*   nvv    = (const int*)d_in[2];
    const float* w0     = (const float*)d_in[3];
    const float* w1     = (const float*)d_in[4];
    const float* nw0    = (const float*)d_in[5];
    const float* nw1    = (const float*)d_in[6];
    const float* gamma0 = (const float*)d_in[7];
    const float* beta0  = (const float*)d_in[8];
    const float* gamma1 = (const float*)d_in[9];
    const float* beta1  = (const float*)d_in[10];
    float* out = (float*)d_out;

    char* ws = (char*)d_ws;
    uint32_t* mask    = (uint32_t*)ws;  ws += (size_t)NB * NW * 4;        // 256 KB
    int*      wbase   = (int*)ws;       ws += (size_t)NB * NW * 4;        // 256 KB
    int*      slin    = (int*)ws;       ws += (size_t)NB * NN * 4;        // 2 MB
    int*      s2o     = (int*)ws;       ws += (size_t)NB * NN * 4;        // 2 MB
    float*    bufA    = (float*)ws;     ws += (size_t)NB * NN * 16 * 4;   // 32 MB (sfeats, then conv2 out)
    float*    bufS    = (float*)ws;     ws += (size_t)NB * NN * 16 * 4;   // 32 MB (sorted conv1 out)
    float*    partials= (float*)ws;     ws += (size_t)2048 * 32 * 4;      // 256 KB
    float*    sb1     = (float*)ws;     ws += 32 * 4;
    float*    sb2     = (float*)ws;     ws += 32 * 4;

    hipMemsetAsync(mask, 0, (size_t)NB * NW * 4, stream);

    dim3 gridBN(NN / 256, NB);
    build_mask_kernel<<<gridBN, 256, 0, stream>>>(xyz, nvv, mask);
    scan_mask_kernel<<<NB, 256, 0, stream>>>(mask, wbase);
    perm_gather_kernel<<<gridBN, 256, 0, stream>>>(xyz, nvv, mask, wbase, feats,
                                                   s2o, slin, bufA);

    // Layer 1: sorted in (bufA) -> sorted out (bufS)
    conv_sorted_kernel<false, false><<<gridBN, 256, 0, stream>>>(
        bufA, slin, nvv, mask, wbase, w0, nw0, nullptr, nullptr, bufS, partials);
    finalize_kernel<<<1, 256, 0, stream>>>(partials, NN / 256 * NB, nvv, gamma0, beta0, sb1);

    // Layer 2: sorted in (bufS, fused BN1+ReLU at gather) -> original-order out (bufA)
    conv_sorted_kernel<true, true><<<gridBN, 256, 0, stream>>>(
        bufS, slin, nvv, mask, wbase, w1, nw1, sb1, s2o, bufA, partials);
    finalize_kernel<<<1, 256, 0, stream>>>(partials, NN / 256 * NB, nvv, gamma1, beta1, sb2);

    bnrelu_kernel<<<(size_t)NB * NN * 16 / 4 / 256, 256, 0, stream>>>(bufA, sb2, nvv, out);
}

// Round 3
// 433.593 us; speedup vs baseline: 1.3930x; 1.3930x over previous
//
#include <hip/hip_runtime.h>
#include <cstdint>
#include <cstddef>

#define NB 8
#define NN 65536
#define NS (NN + 16)         // sorted-buffer row stride (row NN = zero sentinel)
#define GG 64
#define GG3 (GG*GG*GG)
#define NW (GG3/32)          // 8192 mask words per batch
#define NBLK 256             // conv blocks per batch
#define EPSC 1e-3f

typedef __bf16 bf16x8 __attribute__((ext_vector_type(8)));
typedef float  f32x4  __attribute__((ext_vector_type(4)));

__device__ __forceinline__ unsigned short f2bf(float f) {
    unsigned u = __builtin_bit_cast(unsigned, f);
    unsigned r = (u + 0x7fffu + ((u >> 16) & 1u)) >> 16;
    return (unsigned short)r;
}
__device__ __forceinline__ unsigned pk2(float a, float b) {
    return (unsigned)f2bf(a) | ((unsigned)f2bf(b) << 16);
}

// rank of active site lin within batch, or -1 if inactive.
__device__ __forceinline__ int site_rank(const uint32_t* __restrict__ mb,
                                         const int* __restrict__ wb, int lin) {
    uint32_t w = mb[lin >> 5];
    uint32_t bit = 1u << (lin & 31);
    if (!(w & bit)) return -1;
    return wb[lin >> 5] + __popc(w & (bit - 1u));
}

// ---------------------------------------------------------------------------
// K1: occupancy bitmask (mask pre-memset to 0)
// ---------------------------------------------------------------------------
__global__ __launch_bounds__(256) void build_mask_kernel(
    const int* __restrict__ xyz, const int* __restrict__ nvv,
    uint32_t* __restrict__ mask)
{
    int b = blockIdx.y;
    int n = blockIdx.x * 256 + threadIdx.x;
    if (n < nvv[b]) {
        const int* cp = xyz + ((size_t)b * NN + n) * 3;
        int lin = cp[0] * (GG * GG) + cp[1] * GG + cp[2];
        atomicOr(&mask[b * NW + (lin >> 5)], 1u << (lin & 31));
    }
}

// ---------------------------------------------------------------------------
// K2: exclusive prefix sum of popcounts over the 8192 words of one batch
// ---------------------------------------------------------------------------
__global__ __launch_bounds__(256) void scan_mask_kernel(
    const uint32_t* __restrict__ mask, int* __restrict__ wbase)
{
    int b = blockIdx.x;
    const uint32_t* mb = mask + (size_t)b * NW;
    int* wb = wbase + (size_t)b * NW;
    int t = threadIdx.x;

    int cnts[32];
    int local = 0;
    #pragma unroll
    for (int i = 0; i < 32; i++) { cnts[i] = __popc(mb[t * 32 + i]); local += cnts[i]; }

    __shared__ int sc[256];
    sc[t] = local;
    __syncthreads();
    for (int off = 1; off < 256; off <<= 1) {
        int v = (t >= off) ? sc[t - off] : 0;
        __syncthreads();
        sc[t] += v;
        __syncthreads();
    }
    int base = sc[t] - local;   // exclusive
    #pragma unroll
    for (int i = 0; i < 32; i++) { wb[t * 32 + i] = base; base += cnts[i]; }
}

// ---------------------------------------------------------------------------
// K3: pack both layers' weights into MFMA B-fragment layout (bf16).
// wf[s][i][lane][j] = w_s[off=2i+(quad>>1)][c=(quad&1)*8+j][n=lane&15]
// ---------------------------------------------------------------------------
__global__ void wfrag_kernel(const float* __restrict__ w0,
                             const float* __restrict__ w1,
                             unsigned short* __restrict__ wf)
{
    int L = threadIdx.x;           // 64 threads
    int quad = L >> 4, n = L & 15;
    for (int s = 0; s < 2; s++) {
        const float* w = s ? w1 : w0;
        unsigned short* o = wf + s * 14 * 512;
        for (int i = 0; i < 14; i++) {
            int off = 2 * i + (quad >> 1);
            for (int j = 0; j < 8; j++) {
                int c = ((quad & 1) << 3) + j;
                float v = (off < 27) ? w[(off * 16 + c) * 16 + n] : 0.f;
                o[i * 512 + L * 8 + j] = f2bf(v);
            }
        }
    }
}

// ---------------------------------------------------------------------------
// K4: permutation + gather feats (fp32) into rank-sorted bf16 rows.
// Rows [cnt, NN] of each batch are zeroed (row NN = gather sentinel).
// ---------------------------------------------------------------------------
__global__ __launch_bounds__(256) void perm_gather_kernel(
    const int* __restrict__ xyz, const int* __restrict__ nvv,
    const uint32_t* __restrict__ mask, const int* __restrict__ wbase,
    const float* __restrict__ feats,
    int* __restrict__ s2o, int* __restrict__ slin,
    unsigned short* __restrict__ sfeats)
{
    int b = blockIdx.y;
    int n = blockIdx.x * 256 + threadIdx.x;
    int cnt = nvv[b];
    unsigned short* sfb = sfeats + (size_t)b * NS * 16;
    if (blockIdx.x == 0 && threadIdx.x < 16)
        sfb[(size_t)NN * 16 + threadIdx.x] = 0;     // sentinel row
    if (n < cnt) {
        const int* cp = xyz + ((size_t)b * NN + n) * 3;
        int lin = cp[0] * (GG * GG) + cp[1] * GG + cp[2];
        int r = site_rank(mask + (size_t)b * NW, wbase + (size_t)b * NW, lin);
        s2o[(size_t)b * NN + r] = n;
        slin[(size_t)b * NN + r] = lin;
        const float4* fp = (const float4*)(feats + ((size_t)b * NN + n) * 16);
        float4 f0 = fp[0], f1 = fp[1], f2 = fp[2], f3 = fp[3];
        uint4 lo = make_uint4(pk2(f0.x, f0.y), pk2(f0.z, f0.w),
                              pk2(f1.x, f1.y), pk2(f1.z, f1.w));
        uint4 hi = make_uint4(pk2(f2.x, f2.y), pk2(f2.z, f2.w),
                              pk2(f3.x, f3.y), pk2(f3.z, f3.w));
        *(uint4*)(sfb + (size_t)r * 16)     = lo;
        *(uint4*)(sfb + (size_t)r * 16 + 8) = hi;
    } else {
        uint4 z = make_uint4(0, 0, 0, 0);
        *(uint4*)(sfb + (size_t)n * 16)     = z;
        *(uint4*)(sfb + (size_t)n * 16 + 8) = z;
    }
}

// ---------------------------------------------------------------------------
// K5/K8: MFMA sparse conv. One wave = 16 voxels/tile, 4 tiles/wave.
// K=32 packs two offsets; 14 MFMAs cover all 27 (+1 zero pad).
// Fuses ones-conv normalizer and BN partial stats.
// ---------------------------------------------------------------------------
template<bool SCATTER>
__global__ __launch_bounds__(256, 4) void conv_mfma_kernel(
    const unsigned short* __restrict__ sfeats,  // (B,NS,16) bf16 rank-sorted
    const int*      __restrict__ slin,          // (B,NN) rank -> lin
    const int*      __restrict__ nvv,
    const uint32_t* __restrict__ mask,
    const int*      __restrict__ wbase,
    const unsigned short* __restrict__ wfrag,   // 14*512 bf16 B-frags
    const float*    __restrict__ nw,            // (27,)
    const int*      __restrict__ s2o,           // rank -> original row
    float*          __restrict__ outbuf,        // (B,NN,16) fp32
    float*          __restrict__ partials)      // (B*NBLK, 32)
{
    int b = blockIdx.y;
    int cnt = nvv[b];
    int lane = threadIdx.x & 63;
    int wv = threadIdx.x >> 6;
    int m = lane & 15, quad = lane >> 4;       // m: voxel row / out channel
    int wib = blockIdx.x * 4 + wv;             // wave index in batch [0,1024)

    __shared__ int   jj[4][16][28];
    __shared__ float rrl[4][16];
    __shared__ float red[4][32];

    const uint32_t* mb  = mask  + (size_t)b * NW;
    const int*      wbs = wbase + (size_t)b * NW;
    const unsigned short* fb = sfeats + (size_t)b * NS * 16;

    // B-fragments: loaded once per wave, held in VGPRs
    bf16x8 bfr[14];
    #pragma unroll
    for (int i = 0; i < 14; i++)
        bfr[i] = *(const bf16x8*)(wfrag + i * 512 + lane * 8);

    float psum = 0.f, psq = 0.f;
    int coff = (quad & 1) << 3;

    for (int tile = wib; tile < NN / 16; tile += 4 * NBLK) {
        int r0 = tile << 4;
        if (r0 >= cnt) continue;

        // ---- rank phase: lane handles voxel m, offsets quad+4t ----
        int R = r0 + m;
        bool vld = R < cnt;
        int lin = vld ? slin[(size_t)b * NN + R] : 0;
        int x = lin >> 12, y = (lin >> 6) & 63, z = lin & 63;
        float ncl = 0.f;
        #pragma unroll
        for (int t = 0; t < 7; t++) {
            int off = quad + (t << 2);
            bool act = off < 27;
            int offc = act ? off : 0;
            int dx = offc / 9 - 1, dy = (offc / 3) % 3 - 1, dz = offc % 3 - 1;
            int nx = x + dx, ny = y + dy, nz = z + dz;
            bool inb = ((unsigned)nx < 64u) & ((unsigned)ny < 64u) & ((unsigned)nz < 64u);
            int nlin = (nx << 12) + (ny << 6) + nz;
            nlin = inb ? nlin : 0;
            uint32_t mw = mb[nlin >> 5];
            uint32_t bit = 1u << (nlin & 31);
            bool hit = vld & inb & ((mw & bit) != 0u);
            int rnk = wbs[nlin >> 5] + __popc(mw & (bit - 1u));
            int jv = hit ? rnk : NN;           // sentinel = zero row
            if (act) {
                jj[wv][m][off] = jv;
                ncl += hit ? nw[off] : 0.f;
            }
        }
        ncl += __shfl_xor(ncl, 16, 64);
        ncl += __shfl_xor(ncl, 32, 64);
        if (quad == 0) rrl[wv][m] = 1.f / (1.f + fabsf(ncl));

        // ---- compute phase: 14 MFMAs, per-lane 16B gathers ----
        f32x4 acc = {0.f, 0.f, 0.f, 0.f};
        #pragma unroll
        for (int i = 0; i < 14; i++) {
            int off = 2 * i + (quad >> 1);
            int j = jj[wv][m][off < 27 ? off : 27];
            j = (off < 27) ? j : NN;
            bf16x8 av = *(const bf16x8*)(fb + (size_t)j * 16 + coff);
            acc = __builtin_amdgcn_mfma_f32_16x16x32_bf16(av, bfr[i], acc, 0, 0, 0);
        }

        // ---- epilogue: D[row=quad*4+r][ch=m] ----
        #pragma unroll
        for (int r4 = 0; r4 < 4; r4++) {
            int row = (quad << 2) + r4;
            int Rr = r0 + row;
            float tval = acc[r4] * rrl[wv][row];
            psum += tval; psq += tval * tval;
            if (Rr < cnt) {
                int orow = SCATTER ? s2o[(size_t)b * NN + Rr] : Rr;
                outbuf[((size_t)b * NN + orow) * 16 + m] = tval;
            }
        }
    }

    // ---- BN partial stats ----
    psum += __shfl_xor(psum, 16, 64); psum += __shfl_xor(psum, 32, 64);
    psq  += __shfl_xor(psq, 16, 64);  psq  += __shfl_xor(psq, 32, 64);
    if (lane < 16) { red[wv][lane] = psum; red[wv][16 + lane] = psq; }
    __syncthreads();
    if (threadIdx.x < 32) {
        float v = red[0][threadIdx.x] + red[1][threadIdx.x] +
                  red[2][threadIdx.x] + red[3][threadIdx.x];
        partials[((size_t)b * gridDim.x + blockIdx.x) * 32 + threadIdx.x] = v;
    }
}

// ---------------------------------------------------------------------------
// K6/K9: reduce partials -> per-channel scale/bias (single block)
// ---------------------------------------------------------------------------
__global__ __launch_bounds__(256) void finalize_kernel(
    const float* __restrict__ partials, int nparts,
    const int*   __restrict__ nvv,
    const float* __restrict__ gamma, const float* __restrict__ beta,
    float*       __restrict__ sb)     // sb[0:16]=scale, sb[16:32]=bias
{
    __shared__ float red[8][32];
    __shared__ float tot[32];
    int s = threadIdx.x & 31;
    int ch = threadIdx.x >> 5;
    float v = 0.f;
    for (int r = ch; r < nparts; r += 8)
        v += partials[(size_t)r * 32 + s];
    red[ch][s] = v;
    __syncthreads();
    if (threadIdx.x < 32) {
        float x = 0.f;
        #pragma unroll
        for (int k = 0; k < 8; k++) x += red[k][threadIdx.x];
        tot[threadIdx.x] = x;
    }
    __syncthreads();
    if (threadIdx.x < 16) {
        float cnt = 0.f;
        #pragma unroll
        for (int b = 0; b < NB; b++) cnt += (float)nvv[b];
        float mean = tot[threadIdx.x] / cnt;
        float var  = tot[16 + threadIdx.x] / cnt - mean * mean;
        var = fmaxf(var, 0.f);
        float scv = gamma[threadIdx.x] * rsqrtf(var + EPSC);
        sb[threadIdx.x]      = scv;
        sb[16 + threadIdx.x] = beta[threadIdx.x] - mean * scv;
    }
}

// ---------------------------------------------------------------------------
// K7: BN+ReLU on sorted fp32 conv1 out -> sorted bf16 (rows [cnt,NN] zeroed)
// ---------------------------------------------------------------------------
__global__ __launch_bounds__(256) void bnrelu_sorted_kernel(
    const float* __restrict__ in, const float* __restrict__ sb,
    const int* __restrict__ nvv, unsigned short* __restrict__ outb)
{
    int b = blockIdx.y;
    int r = blockIdx.x * 256 + threadIdx.x;
    if (r > NN) return;
    int cnt = nvv[b];
    uint4 lo = make_uint4(0, 0, 0, 0), hi = lo;
    if (r < cnt) {
        const float4* ip = (const float4*)(in + ((size_t)b * NN + r) * 16);
        float4 xs[4] = {ip[0], ip[1], ip[2], ip[3]};
        float y[16];
        const float* xf = (const float*)xs;
        #pragma unroll
        for (int c = 0; c < 16; c++)
            y[c] = fmaxf(fmaf(xf[c], sb[c], sb[16 + c]), 0.f);
        lo = make_uint4(pk2(y[0], y[1]), pk2(y[2], y[3]), pk2(y[4], y[5]), pk2(y[6], y[7]));
        hi = make_uint4(pk2(y[8], y[9]), pk2(y[10], y[11]), pk2(y[12], y[13]), pk2(y[14], y[15]));
    }
    unsigned short* op = outb + ((size_t)b * NS + r) * 16;
    *(uint4*)op       = lo;
    *(uint4*)(op + 8) = hi;
}

// ---------------------------------------------------------------------------
// K10: final y = relu(x*scale + bias) for valid rows, zeros elsewhere
// ---------------------------------------------------------------------------
__global__ __launch_bounds__(256) void bnrelu_kernel(
    const float* __restrict__ in, const float* __restrict__ sb,
    const int* __restrict__ nvv, float* __restrict__ out)
{
    size_t i = (size_t)blockIdx.x * 256 + threadIdx.x;   // one float4
    int row = (int)(i >> 2);          // b*N + n
    int b = row >> 16;                // N == 65536
    int n = row & (NN - 1);
    int o = ((int)i & 3) * 4;
    float4 y = make_float4(0.f, 0.f, 0.f, 0.f);
    if (n < nvv[b]) {
        float4 x = ((const float4*)in)[i];
        y.x = fmaxf(fmaf(x.x, sb[o + 0], sb[16 + o + 0]), 0.f);
        y.y = fmaxf(fmaf(x.y, sb[o + 1], sb[16 + o + 1]), 0.f);
        y.z = fmaxf(fmaf(x.z, sb[o + 2], sb[16 + o + 2]), 0.f);
        y.w = fmaxf(fmaf(x.w, sb[o + 3], sb[16 + o + 3]), 0.f);
    }
    ((float4*)out)[i] = y;
}

// ---------------------------------------------------------------------------
extern "C" void kernel_launch(void* const* d_in, const int* in_sizes, int n_in,
                              void* d_out, int out_size, void* d_ws, size_t ws_size,
                              hipStream_t stream)
{
    const float* feats  = (const float*)d_in[0];
    const int*   xyz    = (const int*)d_in[1];
    const int*   nvv    = (const int*)d_in[2];
    const float* w0     = (const float*)d_in[3];
    const float* w1     = (const float*)d_in[4];
    const float* nw0    = (const float*)d_in[5];
    const float* nw1    = (const float*)d_in[6];
    const float* gamma0 = (const float*)d_in[7];
    const float* beta0  = (const float*)d_in[8];
    const float* gamma1 = (const float*)d_in[9];
    const float* beta1  = (const float*)d_in[10];
    float* out = (float*)d_out;

    char* ws = (char*)d_ws;
    uint32_t* mask    = (uint32_t*)ws;       ws += (size_t)NB * NW * 4;        // 256 KB
    int*      wbase   = (int*)ws;            ws += (size_t)NB * NW * 4;        // 256 KB
    int*      slin    = (int*)ws;            ws += (size_t)NB * NN * 4;        // 2 MB
    int*      s2o     = (int*)ws;            ws += (size_t)NB * NN * 4;        // 2 MB
    unsigned short* sfA = (unsigned short*)ws; ws += (size_t)NB * NS * 16 * 2; // 16.8 MB
    unsigned short* sfB = (unsigned short*)ws; ws += (size_t)NB * NS * 16 * 2; // 16.8 MB
    float*    cvout   = (float*)ws;          ws += (size_t)NB * NN * 16 * 4;   // 32 MB (shared conv1/conv2 out)
    unsigned short* wfr = (unsigned short*)ws; ws += (size_t)2 * 14 * 512 * 2; // 28 KB
    float*    partials= (float*)ws;          ws += (size_t)NB * NBLK * 32 * 4; // 256 KB
    float*    sb1     = (float*)ws;          ws += 32 * 4;
    float*    sb2     = (float*)ws;          ws += 32 * 4;

    hipMemsetAsync(mask, 0, (size_t)NB * NW * 4, stream);

    dim3 gridBN(NN / 256, NB);
    build_mask_kernel<<<gridBN, 256, 0, stream>>>(xyz, nvv, mask);
    scan_mask_kernel<<<NB, 256, 0, stream>>>(mask, wbase);
    wfrag_kernel<<<1, 64, 0, stream>>>(w0, w1, wfr);
    perm_gather_kernel<<<gridBN, 256, 0, stream>>>(xyz, nvv, mask, wbase, feats,
                                                   s2o, slin, sfA);

    dim3 gridCV(NBLK, NB);
    // Layer 1: sorted bf16 in -> sorted fp32 out
    conv_mfma_kernel<false><<<gridCV, 256, 0, stream>>>(
        sfA, slin, nvv, mask, wbase, wfr, nw0, nullptr, cvout, partials);
    finalize_kernel<<<1, 256, 0, stream>>>(partials, NB * NBLK, nvv, gamma0, beta0, sb1);
    bnrelu_sorted_kernel<<<dim3(NN / 256 + 1, NB), 256, 0, stream>>>(cvout, sb1, nvv, sfB);

    // Layer 2: sorted bf16 in -> original-order fp32 out (scatter)
    conv_mfma_kernel<true><<<gridCV, 256, 0, stream>>>(
        sfB, slin, nvv, mask, wbase, wfr + 14 * 512, nw1, s2o, cvout, partials);
    finalize_kernel<<<1, 256, 0, stream>>>(partials, NB * NBLK, nvv, gamma1, beta1, sb2);

    bnrelu_kernel<<<(size_t)NB * NN * 16 / 4 / 256, 256, 0, stream>>>(cvout, sb2, nvv, out);
}

// Round 4
// 302.296 us; speedup vs baseline: 1.9981x; 1.4343x over previous
//
#include <hip/hip_runtime.h>
#include <cstdint>
#include <cstddef>

#define NB 8
#define NN 65536
#define NS (NN + 16)         // sorted-buffer row stride (row NN = zero sentinel)
#define GG 64
#define GG3 (GG*GG*GG)
#define NW (GG3/32)          // 8192 mask words per batch
#define NBLK 2048            // conv blocks total (flat)
#define NTILE (NB * (NN/16)) // 32768 wave-tiles total
#define EPSC 1e-3f

typedef __bf16 bf16x8 __attribute__((ext_vector_type(8)));
typedef float  f32x4  __attribute__((ext_vector_type(4)));

__device__ __forceinline__ unsigned short f2bf(float f) {
    unsigned u = __builtin_bit_cast(unsigned, f);
    unsigned r = (u + 0x7fffu + ((u >> 16) & 1u)) >> 16;
    return (unsigned short)r;
}
__device__ __forceinline__ unsigned pk2(float a, float b) {
    return (unsigned)f2bf(a) | ((unsigned)f2bf(b) << 16);
}
__device__ __forceinline__ float bf2f(unsigned short s) {
    return __builtin_bit_cast(float, (unsigned)s << 16);
}

// rank of active site lin within batch from combined (mask,base) words, or -1.
__device__ __forceinline__ int site_rank2(const int2* __restrict__ mwb, int lin) {
    int2 mw = mwb[lin >> 5];
    uint32_t w = (uint32_t)mw.x;
    uint32_t bit = 1u << (lin & 31);
    if (!(w & bit)) return -1;
    return mw.y + __popc(w & (bit - 1u));
}

// ---------------------------------------------------------------------------
// K1: occupancy bitmask (mask pre-memset to 0)
// ---------------------------------------------------------------------------
__global__ __launch_bounds__(256) void build_mask_kernel(
    const int* __restrict__ xyz, const int* __restrict__ nvv,
    uint32_t* __restrict__ mask)
{
    int b = blockIdx.y;
    int n = blockIdx.x * 256 + threadIdx.x;
    if (n < nvv[b]) {
        const int* cp = xyz + ((size_t)b * NN + n) * 3;
        int lin = cp[0] * (GG * GG) + cp[1] * GG + cp[2];
        atomicOr(&mask[b * NW + (lin >> 5)], 1u << (lin & 31));
    }
}

// ---------------------------------------------------------------------------
// K2: exclusive prefix sum of popcounts -> combined int2 {mask_word, base}
// ---------------------------------------------------------------------------
__global__ __launch_bounds__(256) void scan_mask_kernel(
    const uint32_t* __restrict__ mask, int2* __restrict__ mwb)
{
    int b = blockIdx.x;
    const uint32_t* mb = mask + (size_t)b * NW;
    int2* wb = mwb + (size_t)b * NW;
    int t = threadIdx.x;

    uint32_t wv[32];
    int cnts[32];
    int local = 0;
    #pragma unroll
    for (int i = 0; i < 32; i++) {
        wv[i] = mb[t * 32 + i];
        cnts[i] = __popc(wv[i]);
        local += cnts[i];
    }

    __shared__ int sc[256];
    sc[t] = local;
    __syncthreads();
    for (int off = 1; off < 256; off <<= 1) {
        int v = (t >= off) ? sc[t - off] : 0;
        __syncthreads();
        sc[t] += v;
        __syncthreads();
    }
    int base = sc[t] - local;   // exclusive
    #pragma unroll
    for (int i = 0; i < 32; i++) {
        wb[t * 32 + i] = make_int2((int)wv[i], base);
        base += cnts[i];
    }
}

// ---------------------------------------------------------------------------
// K3: pack both layers' weights into MFMA B-fragment layout (bf16), parallel.
// wf[s][i][lane][j] = w_s[off=2i+(quad>>1)][c=(quad&1)*8+j][n=lane&15]
// ---------------------------------------------------------------------------
__global__ __launch_bounds__(256) void wfrag_kernel(
    const float* __restrict__ w0, const float* __restrict__ w1,
    unsigned short* __restrict__ wf)
{
    int s = blockIdx.x;                    // layer
    const float* w = s ? w1 : w0;
    unsigned short* o = wf + s * 14 * 512;
    for (int idx = threadIdx.x; idx < 14 * 512; idx += 256) {
        int i = idx >> 9;
        int rem = idx & 511;
        int L = rem >> 3, j = rem & 7;
        int quad = L >> 4, n = L & 15;
        int off = 2 * i + (quad >> 1);
        int c = ((quad & 1) << 3) + j;
        float v = (off < 27) ? w[(off * 16 + c) * 16 + n] : 0.f;
        o[idx] = f2bf(v);
    }
}

// ---------------------------------------------------------------------------
// K4: permutation + gather feats (fp32) into rank-sorted bf16 rows.
// srow[r] = {lin, original n}. Rows [cnt, NN] zeroed (row NN = sentinel).
// ---------------------------------------------------------------------------
__global__ __launch_bounds__(256) void perm_gather_kernel(
    const int* __restrict__ xyz, const int* __restrict__ nvv,
    const int2* __restrict__ mwb,
    const float* __restrict__ feats,
    int2* __restrict__ srow,
    unsigned short* __restrict__ sfeats)
{
    int b = blockIdx.y;
    int n = blockIdx.x * 256 + threadIdx.x;
    int cnt = nvv[b];
    unsigned short* sfb = sfeats + (size_t)b * NS * 16;
    if (blockIdx.x == 0 && threadIdx.x < 16)
        sfb[(size_t)NN * 16 + threadIdx.x] = 0;     // sentinel row
    if (n < cnt) {
        const int* cp = xyz + ((size_t)b * NN + n) * 3;
        int lin = cp[0] * (GG * GG) + cp[1] * GG + cp[2];
        int r = site_rank2(mwb + (size_t)b * NW, lin);
        srow[(size_t)b * NN + r] = make_int2(lin, n);
        const float4* fp = (const float4*)(feats + ((size_t)b * NN + n) * 16);
        float4 f0 = fp[0], f1 = fp[1], f2 = fp[2], f3 = fp[3];
        uint4 lo = make_uint4(pk2(f0.x, f0.y), pk2(f0.z, f0.w),
                              pk2(f1.x, f1.y), pk2(f1.z, f1.w));
        uint4 hi = make_uint4(pk2(f2.x, f2.y), pk2(f2.z, f2.w),
                              pk2(f3.x, f3.y), pk2(f3.z, f3.w));
        *(uint4*)(sfb + (size_t)r * 16)     = lo;
        *(uint4*)(sfb + (size_t)r * 16 + 8) = hi;
    } else {
        uint4 z = make_uint4(0, 0, 0, 0);
        *(uint4*)(sfb + (size_t)n * 16)     = z;
        *(uint4*)(sfb + (size_t)n * 16 + 8) = z;
    }
}

// ---------------------------------------------------------------------------
// K5/K8: MFMA sparse conv, flat grid-stride over all (b,tile) wave-tiles.
// One wave = 16 voxels/tile; K=32 packs two offsets; 14 MFMAs.
// Fuses ones-conv normalizer; BN stats accumulated via atomics into stats[32].
// OUTBF16: write sorted bf16 (pre-BN) rows. else fp32; SCATTER via srow.y.
// ---------------------------------------------------------------------------
template<bool SCATTER, bool OUTBF16>
__global__ __launch_bounds__(256, 4) void conv_mfma_kernel(
    const unsigned short* __restrict__ sfeats,  // (B,NS,16) bf16 rank-sorted
    const int2*     __restrict__ srow,          // (B,NN) rank -> {lin, n}
    const int*      __restrict__ nvv,
    const int2*     __restrict__ mwb,           // (B,NW) {mask word, base}
    const unsigned short* __restrict__ wfrag,   // 14*512 bf16 B-frags
    const float*    __restrict__ nw,            // (27,)
    void*           __restrict__ outbuf,
    float*          __restrict__ stats)         // [32] atomic accumulators
{
    int lane = threadIdx.x & 63;
    int wv = threadIdx.x >> 6;
    int m = lane & 15, quad = lane >> 4;       // m: voxel row / out channel
    int wid = blockIdx.x * 4 + wv;             // flat wave id [0, 8192)

    __shared__ int   jj[4][16][29];
    __shared__ float rrl[4][16];
    __shared__ float red[4][32];

    // B-fragments: loaded once per wave, held in VGPRs
    bf16x8 bfr[14];
    #pragma unroll
    for (int i = 0; i < 14; i++)
        bfr[i] = *(const bf16x8*)(wfrag + i * 512 + lane * 8);

    // per-lane offset constants (off = quad + 4t), hoisted out of tile loop
    float nwr[7];
    #pragma unroll
    for (int t = 0; t < 7; t++) {
        int off = quad + (t << 2);
        nwr[t] = (off < 27) ? nw[off] : 0.f;
    }

    float psum = 0.f, psq = 0.f;
    int coff = (quad & 1) << 3;

    for (int ft = wid; ft < NTILE; ft += 4 * NBLK) {
        int b = ft >> 12;                  // NN/16 == 4096 tiles per batch
        int tile = ft & 4095;
        int cnt = nvv[b];
        int r0 = tile << 4;
        if (r0 >= cnt) continue;

        const int2* mb = mwb + (size_t)b * NW;
        const unsigned short* fb = sfeats + (size_t)b * NS * 16;

        // ---- rank phase: lane handles voxel m, offsets quad+4t ----
        int R = r0 + m;
        bool vld = R < cnt;
        int lin = vld ? srow[(size_t)b * NN + R].x : 0;
        int x = lin >> 12, y = (lin >> 6) & 63, z = lin & 63;
        float ncl = 0.f;
        #pragma unroll
        for (int t = 0; t < 7; t++) {
            int off = quad + (t << 2);
            bool act = off < 27;
            int offc = act ? off : 0;
            int dx = offc / 9 - 1, dy = (offc / 3) % 3 - 1, dz = offc % 3 - 1;
            int nx = x + dx, ny = y + dy, nz = z + dz;
            bool inb = ((unsigned)nx < 64u) & ((unsigned)ny < 64u) & ((unsigned)nz < 64u);
            int nlin = (nx << 12) + (ny << 6) + nz;
            nlin = inb ? nlin : 0;
            int2 mw = mb[nlin >> 5];
            uint32_t w = (uint32_t)mw.x;
            uint32_t bit = 1u << (nlin & 31);
            bool hit = vld & inb & ((w & bit) != 0u);
            int rnk = mw.y + __popc(w & (bit - 1u));
            int jv = hit ? rnk : NN;           // sentinel = zero row
            if (act) {
                jj[wv][m][off] = jv;
                ncl += hit ? nwr[t] : 0.f;
            }
        }
        ncl += __shfl_xor(ncl, 16, 64);
        ncl += __shfl_xor(ncl, 32, 64);
        if (quad == 0) rrl[wv][m] = 1.f / (1.f + fabsf(ncl));

        // ---- compute phase: 14 MFMAs, per-lane 16B gathers ----
        f32x4 acc = {0.f, 0.f, 0.f, 0.f};
        #pragma unroll
        for (int i = 0; i < 14; i++) {
            int off = 2 * i + (quad >> 1);
            int j = jj[wv][m][off < 27 ? off : 28];
            j = (off < 27) ? j : NN;
            bf16x8 av = *(const bf16x8*)(fb + (size_t)j * 16 + coff);
            acc = __builtin_amdgcn_mfma_f32_16x16x32_bf16(av, bfr[i], acc, 0, 0, 0);
        }

        // ---- epilogue: D[row=quad*4+r][ch=m] ----
        #pragma unroll
        for (int r4 = 0; r4 < 4; r4++) {
            int row = (quad << 2) + r4;
            int Rr = r0 + row;
            float tval = acc[r4] * rrl[wv][row];
            psum += tval; psq += tval * tval;
            if (Rr < cnt) {
                if (OUTBF16) {
                    unsigned short* ob = (unsigned short*)outbuf;
                    ob[((size_t)b * NN + Rr) * 16 + m] = f2bf(tval);
                } else {
                    float* ob = (float*)outbuf;
                    int orow = SCATTER ? srow[(size_t)b * NN + Rr].y : Rr;
                    ob[((size_t)b * NN + orow) * 16 + m] = tval;
                }
            }
        }
    }

    // ---- BN partial stats: block reduce, then one atomic per slot ----
    psum += __shfl_xor(psum, 16, 64); psum += __shfl_xor(psum, 32, 64);
    psq  += __shfl_xor(psq, 16, 64);  psq  += __shfl_xor(psq, 32, 64);
    if (lane < 16) { red[wv][lane] = psum; red[wv][16 + lane] = psq; }
    __syncthreads();
    if (threadIdx.x < 32) {
        float v = red[0][threadIdx.x] + red[1][threadIdx.x] +
                  red[2][threadIdx.x] + red[3][threadIdx.x];
        atomicAdd(&stats[threadIdx.x], v);
    }
}

// ---------------------------------------------------------------------------
// K6/K9: stats[32] -> per-channel scale/bias (tiny)
// ---------------------------------------------------------------------------
__global__ __launch_bounds__(64) void finalize_kernel(
    const float* __restrict__ stats,
    const int*   __restrict__ nvv,
    const float* __restrict__ gamma, const float* __restrict__ beta,
    float*       __restrict__ sb)     // sb[0:16]=scale, sb[16:32]=bias
{
    if (threadIdx.x < 16) {
        float cnt = 0.f;
        #pragma unroll
        for (int b = 0; b < NB; b++) cnt += (float)nvv[b];
        float mean = stats[threadIdx.x] / cnt;
        float var  = stats[16 + threadIdx.x] / cnt - mean * mean;
        var = fmaxf(var, 0.f);
        float scv = gamma[threadIdx.x] * rsqrtf(var + EPSC);
        sb[threadIdx.x]      = scv;
        sb[16 + threadIdx.x] = beta[threadIdx.x] - mean * scv;
    }
}

// ---------------------------------------------------------------------------
// K7: BN+ReLU on sorted bf16 conv1 out -> sorted bf16 (rows [cnt,NN] zeroed)
// ---------------------------------------------------------------------------
__global__ __launch_bounds__(256) void bnrelu_sorted_kernel(
    const unsigned short* __restrict__ in, const float* __restrict__ sb,
    const int* __restrict__ nvv, unsigned short* __restrict__ outb)
{
    int b = blockIdx.y;
    int r = blockIdx.x * 256 + threadIdx.x;
    if (r > NN) return;
    int cnt = nvv[b];
    uint4 lo = make_uint4(0, 0, 0, 0), hi = lo;
    if (r < cnt) {
        const uint4* ip = (const uint4*)(in + ((size_t)b * NN + r) * 16);
        uint4 xl = ip[0], xh = ip[1];
        const unsigned* xu = (const unsigned*)&xl;
        float y[16];
        #pragma unroll
        for (int c = 0; c < 8; c++) {
            unsigned u = ((const unsigned*)&xl)[c & 3];
            (void)u;
        }
        #pragma unroll
        for (int c = 0; c < 16; c++) {
            unsigned u = (c < 8) ? ((const unsigned*)&xl)[c >> 1]
                                 : ((const unsigned*)&xh)[(c - 8) >> 1];
            unsigned short sv = (c & 1) ? (unsigned short)(u >> 16)
                                        : (unsigned short)(u & 0xffff);
            float xf = bf2f(sv);
            y[c] = fmaxf(fmaf(xf, sb[c], sb[16 + c]), 0.f);
        }
        (void)xu;
        lo = make_uint4(pk2(y[0], y[1]), pk2(y[2], y[3]), pk2(y[4], y[5]), pk2(y[6], y[7]));
        hi = make_uint4(pk2(y[8], y[9]), pk2(y[10], y[11]), pk2(y[12], y[13]), pk2(y[14], y[15]));
    }
    unsigned short* op = outb + ((size_t)b * NS + r) * 16;
    *(uint4*)op       = lo;
    *(uint4*)(op + 8) = hi;
}

// ---------------------------------------------------------------------------
// K10: final y = relu(x*scale + bias) for valid rows, zeros elsewhere
// ---------------------------------------------------------------------------
__global__ __launch_bounds__(256) void bnrelu_kernel(
    const float* __restrict__ in, const float* __restrict__ sb,
    const int* __restrict__ nvv, float* __restrict__ out)
{
    size_t i = (size_t)blockIdx.x * 256 + threadIdx.x;   // one float4
    int row = (int)(i >> 2);          // b*N + n
    int b = row >> 16;                // N == 65536
    int n = row & (NN - 1);
    int o = ((int)i & 3) * 4;
    float4 y = make_float4(0.f, 0.f, 0.f, 0.f);
    if (n < nvv[b]) {
        float4 x = ((const float4*)in)[i];
        y.x = fmaxf(fmaf(x.x, sb[o + 0], sb[16 + o + 0]), 0.f);
        y.y = fmaxf(fmaf(x.y, sb[o + 1], sb[16 + o + 1]), 0.f);
        y.z = fmaxf(fmaf(x.z, sb[o + 2], sb[16 + o + 2]), 0.f);
        y.w = fmaxf(fmaf(x.w, sb[o + 3], sb[16 + o + 3]), 0.f);
    }
    ((float4*)out)[i] = y;
}

// ---------------------------------------------------------------------------
extern "C" void kernel_launch(void* const* d_in, const int* in_sizes, int n_in,
                              void* d_out, int out_size, void* d_ws, size_t ws_size,
                              hipStream_t stream)
{
    const float* feats  = (const float*)d_in[0];
    const int*   xyz    = (const int*)d_in[1];
    const int*   nvv    = (const int*)d_in[2];
    const float* w0     = (const float*)d_in[3];
    const float* w1     = (const float*)d_in[4];
    const float* nw0    = (const float*)d_in[5];
    const float* nw1    = (const float*)d_in[6];
    const float* gamma0 = (const float*)d_in[7];
    const float* beta0  = (const float*)d_in[8];
    const float* gamma1 = (const float*)d_in[9];
    const float* beta1  = (const float*)d_in[10];
    float* out = (float*)d_out;

    char* ws = (char*)d_ws;
    uint32_t* mask    = (uint32_t*)ws;       ws += (size_t)NB * NW * 4;        // 256 KB (memset 0)
    float*    stats1  = (float*)ws;          ws += 32 * 4;                     // (memset 0)
    float*    stats2  = (float*)ws;          ws += 32 * 4;                     // (memset 0)
    int2*     mwb     = (int2*)ws;           ws += (size_t)NB * NW * 8;        // 512 KB
    int2*     srow    = (int2*)ws;           ws += (size_t)NB * NN * 8;        // 4 MB
    unsigned short* sfA = (unsigned short*)ws; ws += (size_t)NB * NS * 16 * 2; // 16.8 MB
    unsigned short* sfB = (unsigned short*)ws; ws += (size_t)NB * NS * 16 * 2; // 16.8 MB
    char*     regC    = ws;                  ws += (size_t)NB * NN * 16 * 4;   // 32 MB (union)
    unsigned short* bufPre = (unsigned short*)regC;  // conv1 sorted bf16 out (16 MB)
    float*    cvout   = (float*)regC;                // conv2 fp32 out (32 MB)
    unsigned short* wfr = (unsigned short*)ws; ws += (size_t)2 * 14 * 512 * 2; // 28 KB
    float*    sb1     = (float*)ws;          ws += 32 * 4;
    float*    sb2     = (float*)ws;          ws += 32 * 4;

    // zero mask + both stats accumulators in one memset
    hipMemsetAsync(mask, 0, (size_t)NB * NW * 4 + 256, stream);

    dim3 gridBN(NN / 256, NB);
    build_mask_kernel<<<gridBN, 256, 0, stream>>>(xyz, nvv, mask);
    scan_mask_kernel<<<NB, 256, 0, stream>>>(mask, mwb);
    wfrag_kernel<<<2, 256, 0, stream>>>(w0, w1, wfr);
    perm_gather_kernel<<<gridBN, 256, 0, stream>>>(xyz, nvv, mwb, feats, srow, sfA);

    // Layer 1: sorted bf16 in -> sorted bf16 (pre-BN) out
    conv_mfma_kernel<false, true><<<NBLK, 256, 0, stream>>>(
        sfA, srow, nvv, mwb, wfr, nw0, bufPre, stats1);
    finalize_kernel<<<1, 64, 0, stream>>>(stats1, nvv, gamma0, beta0, sb1);
    bnrelu_sorted_kernel<<<dim3(NN / 256 + 1, NB), 256, 0, stream>>>(bufPre, sb1, nvv, sfB);

    // Layer 2: sorted bf16 in -> original-order fp32 out (scatter)
    conv_mfma_kernel<true, false><<<NBLK, 256, 0, stream>>>(
        sfB, srow, nvv, mwb, wfr + 14 * 512, nw1, cvout, stats2);
    finalize_kernel<<<1, 64, 0, stream>>>(stats2, nvv, gamma1, beta1, sb2);

    bnrelu_kernel<<<(size_t)NB * NN * 16 / 4 / 256, 256, 0, stream>>>(cvout, sb2, nvv, out);
}

// Round 5
// 299.661 us; speedup vs baseline: 2.0156x; 1.0088x over previous
//
#include <hip/hip_runtime.h>
#include <cstdint>
#include <cstddef>

#define NB 8
#define NN 65536
#define NS (NN + 16)         // sorted-buffer row stride (row NN = zero sentinel)
#define GG 64
#define GG3 (GG*GG*GG)
#define NW (GG3/32)          // 8192 mask words per batch
#define NBLKC 1024           // conv blocks (fully resident: 4/CU)
#define NP32 (NB * 2048)     // 32-voxel tile-pairs total
#define EPSC 1e-3f

typedef __bf16 bf16x8 __attribute__((ext_vector_type(8)));
typedef float  f32x4  __attribute__((ext_vector_type(4)));

__device__ __forceinline__ unsigned short f2bf(float f) {
    unsigned u = __builtin_bit_cast(unsigned, f);
    unsigned r = (u + 0x7fffu + ((u >> 16) & 1u)) >> 16;
    return (unsigned short)r;
}
__device__ __forceinline__ unsigned pk2(float a, float b) {
    return (unsigned)f2bf(a) | ((unsigned)f2bf(b) << 16);
}
__device__ __forceinline__ float bf2f(unsigned short s) {
    return __builtin_bit_cast(float, (unsigned)s << 16);
}

__device__ __forceinline__ int site_rank2(const int2* __restrict__ mwb, int lin) {
    int2 mw = mwb[lin >> 5];
    uint32_t w = (uint32_t)mw.x;
    uint32_t bit = 1u << (lin & 31);
    if (!(w & bit)) return -1;
    return mw.y + __popc(w & (bit - 1u));
}

// ---------------------------------------------------------------------------
// K1: occupancy bitmask (mask pre-memset to 0)
// ---------------------------------------------------------------------------
__global__ __launch_bounds__(256) void build_mask_kernel(
    const int* __restrict__ xyz, const int* __restrict__ nvv,
    uint32_t* __restrict__ mask)
{
    int b = blockIdx.y;
    int n = blockIdx.x * 256 + threadIdx.x;
    if (n < nvv[b]) {
        const int* cp = xyz + ((size_t)b * NN + n) * 3;
        int lin = cp[0] * (GG * GG) + cp[1] * GG + cp[2];
        atomicOr(&mask[b * NW + (lin >> 5)], 1u << (lin & 31));
    }
}

// ---------------------------------------------------------------------------
// K2: exclusive prefix sum of popcounts -> combined int2 {mask_word, base}
// ---------------------------------------------------------------------------
__global__ __launch_bounds__(256) void scan_mask_kernel(
    const uint32_t* __restrict__ mask, int2* __restrict__ mwb)
{
    int b = blockIdx.x;
    const uint32_t* mb = mask + (size_t)b * NW;
    int2* wb = mwb + (size_t)b * NW;
    int t = threadIdx.x;

    uint32_t wv[32];
    int cnts[32];
    int local = 0;
    #pragma unroll
    for (int i = 0; i < 32; i++) {
        wv[i] = mb[t * 32 + i];
        cnts[i] = __popc(wv[i]);
        local += cnts[i];
    }

    __shared__ int sc[256];
    sc[t] = local;
    __syncthreads();
    for (int off = 1; off < 256; off <<= 1) {
        int v = (t >= off) ? sc[t - off] : 0;
        __syncthreads();
        sc[t] += v;
        __syncthreads();
    }
    int base = sc[t] - local;   // exclusive
    #pragma unroll
    for (int i = 0; i < 32; i++) {
        wb[t * 32 + i] = make_int2((int)wv[i], base);
        base += cnts[i];
    }
}

// ---------------------------------------------------------------------------
// K3: pack both layers' weights into MFMA B-fragment layout (bf16).
// wf[s][i][lane][j] = w_s[off=2i+(quad>>1)][c=(quad&1)*8+j][n=lane&15]
// ---------------------------------------------------------------------------
__global__ __launch_bounds__(256) void wfrag_kernel(
    const float* __restrict__ w0, const float* __restrict__ w1,
    unsigned short* __restrict__ wf)
{
    int s = blockIdx.x;                    // layer
    const float* w = s ? w1 : w0;
    unsigned short* o = wf + s * 14 * 512;
    for (int idx = threadIdx.x; idx < 14 * 512; idx += 256) {
        int i = idx >> 9;
        int rem = idx & 511;
        int L = rem >> 3, j = rem & 7;
        int quad = L >> 4, n = L & 15;
        int off = 2 * i + (quad >> 1);
        int c = ((quad & 1) << 3) + j;
        float v = (off < 27) ? w[(off * 16 + c) * 16 + n] : 0.f;
        o[idx] = f2bf(v);
    }
}

// ---------------------------------------------------------------------------
// K4: permutation + gather feats (fp32) into rank-sorted bf16 rows.
// srow[r] = {lin, original n}. Rows [cnt, NN] zeroed (row NN = sentinel).
// ---------------------------------------------------------------------------
__global__ __launch_bounds__(256) void perm_gather_kernel(
    const int* __restrict__ xyz, const int* __restrict__ nvv,
    const int2* __restrict__ mwb,
    const float* __restrict__ feats,
    int2* __restrict__ srow,
    unsigned short* __restrict__ sfeats)
{
    int b = blockIdx.y;
    int n = blockIdx.x * 256 + threadIdx.x;
    int cnt = nvv[b];
    unsigned short* sfb = sfeats + (size_t)b * NS * 16;
    if (blockIdx.x == 0 && threadIdx.x < 16)
        sfb[(size_t)NN * 16 + threadIdx.x] = 0;     // sentinel row
    if (n < cnt) {
        const int* cp = xyz + ((size_t)b * NN + n) * 3;
        int lin = cp[0] * (GG * GG) + cp[1] * GG + cp[2];
        int r = site_rank2(mwb + (size_t)b * NW, lin);
        srow[(size_t)b * NN + r] = make_int2(lin, n);
        const float4* fp = (const float4*)(feats + ((size_t)b * NN + n) * 16);
        float4 f0 = fp[0], f1 = fp[1], f2 = fp[2], f3 = fp[3];
        uint4 lo = make_uint4(pk2(f0.x, f0.y), pk2(f0.z, f0.w),
                              pk2(f1.x, f1.y), pk2(f1.z, f1.w));
        uint4 hi = make_uint4(pk2(f2.x, f2.y), pk2(f2.z, f2.w),
                              pk2(f3.x, f3.y), pk2(f3.z, f3.w));
        *(uint4*)(sfb + (size_t)r * 16)     = lo;
        *(uint4*)(sfb + (size_t)r * 16 + 8) = hi;
    } else {
        uint4 z = make_uint4(0, 0, 0, 0);
        *(uint4*)(sfb + (size_t)n * 16)     = z;
        *(uint4*)(sfb + (size_t)n * 16 + 8) = z;
    }
}

// ---------------------------------------------------------------------------
// K5/K7: MFMA sparse conv, pair-of-tiles (32 ranks) per wave iteration for
// 2x memory-level parallelism + consecutive-window L1 reuse.
// Output: sorted bf16 pre-BN rows. BN stats via 16-way striped atomics.
// ---------------------------------------------------------------------------
__global__ __launch_bounds__(256, 4) void conv_mfma_kernel(
    const unsigned short* __restrict__ sfeats,  // (B,NS,16) bf16 rank-sorted
    const int2*     __restrict__ srow,          // (B,NN) rank -> {lin, n}
    const int*      __restrict__ nvv,
    const int2*     __restrict__ mwb,           // (B,NW) {mask word, base}
    const unsigned short* __restrict__ wfrag,   // 14*512 bf16 B-frags
    const float*    __restrict__ nw,            // (27,)
    unsigned short* __restrict__ outbuf,        // (B,NN,16) bf16 pre-BN sorted
    float*          __restrict__ stats)         // [16][32] striped accumulators
{
    int lane = threadIdx.x & 63;
    int wv = threadIdx.x >> 6;
    int m = lane & 15, quad = lane >> 4;       // m: voxel row / out channel
    int wid = blockIdx.x * 4 + wv;             // flat wave id [0, 4096)

    __shared__ int   jj[4][32][29];
    __shared__ float rrl[4][32];
    __shared__ float red[4][32];

    // B-fragments: loaded once per wave, held in registers
    bf16x8 bfr[14];
    #pragma unroll
    for (int i = 0; i < 14; i++)
        bfr[i] = *(const bf16x8*)(wfrag + i * 512 + lane * 8);

    float nwr[7];
    #pragma unroll
    for (int t = 0; t < 7; t++) {
        int off = quad + (t << 2);
        nwr[t] = (off < 27) ? nw[off] : 0.f;
    }

    float psum = 0.f, psq = 0.f;
    int coff = (quad & 1) << 3;

    for (int pb = wid; pb < NP32; pb += 4096) {
        int b = pb >> 11;                  // 2048 pair-tiles per batch
        int r0 = (pb & 2047) << 5;         // 32 ranks per pair
        int cnt = nvv[b];
        if (r0 >= cnt) continue;

        const int2* mb = mwb + (size_t)b * NW;
        const unsigned short* fb = sfeats + (size_t)b * NS * 16;
        const int2* sr = srow + (size_t)b * NN;

        // ---- rank phase: lane handles voxels m and m+16, offsets quad+4t ----
        int R0 = r0 + m, R1 = r0 + 16 + m;
        bool v0 = R0 < cnt, v1 = R1 < cnt;
        int lin0 = v0 ? sr[R0].x : 0;
        int lin1 = v1 ? sr[R1].x : 0;
        int x0 = lin0 >> 12, y0 = (lin0 >> 6) & 63, z0 = lin0 & 63;
        int x1 = lin1 >> 12, y1 = (lin1 >> 6) & 63, z1 = lin1 & 63;
        float nc0 = 0.f, nc1 = 0.f;
        #pragma unroll
        for (int t = 0; t < 7; t++) {
            int off = quad + (t << 2);
            bool act = off < 27;
            int offc = act ? off : 0;
            int dx = offc / 9 - 1, dy = (offc / 3) % 3 - 1, dz = offc % 3 - 1;

            int nx0 = x0 + dx, ny0 = y0 + dy, nz0 = z0 + dz;
            bool ib0 = ((unsigned)nx0 < 64u) & ((unsigned)ny0 < 64u) & ((unsigned)nz0 < 64u);
            int nl0 = ib0 ? ((nx0 << 12) + (ny0 << 6) + nz0) : 0;
            int2 mw0 = mb[nl0 >> 5];
            uint32_t b0 = 1u << (nl0 & 31);
            bool h0 = v0 & ib0 & (((uint32_t)mw0.x & b0) != 0u);
            int j0 = h0 ? (mw0.y + __popc((uint32_t)mw0.x & (b0 - 1u))) : NN;

            int nx1 = x1 + dx, ny1 = y1 + dy, nz1 = z1 + dz;
            bool ib1 = ((unsigned)nx1 < 64u) & ((unsigned)ny1 < 64u) & ((unsigned)nz1 < 64u);
            int nl1 = ib1 ? ((nx1 << 12) + (ny1 << 6) + nz1) : 0;
            int2 mw1 = mb[nl1 >> 5];
            uint32_t b1 = 1u << (nl1 & 31);
            bool h1 = v1 & ib1 & (((uint32_t)mw1.x & b1) != 0u);
            int j1 = h1 ? (mw1.y + __popc((uint32_t)mw1.x & (b1 - 1u))) : NN;

            if (act) {
                jj[wv][m][off]      = j0;
                jj[wv][m + 16][off] = j1;
                nc0 += h0 ? nwr[t] : 0.f;
                nc1 += h1 ? nwr[t] : 0.f;
            }
        }
        nc0 += __shfl_xor(nc0, 16, 64); nc0 += __shfl_xor(nc0, 32, 64);
        nc1 += __shfl_xor(nc1, 16, 64); nc1 += __shfl_xor(nc1, 32, 64);
        if (quad == 0) {
            rrl[wv][m]      = 1.f / (1.f + fabsf(nc0));
            rrl[wv][m + 16] = 1.f / (1.f + fabsf(nc1));
        }

        // ---- compute phase: 28 gathers + 28 MFMAs (two independent chains) ----
        f32x4 acc0 = {0.f, 0.f, 0.f, 0.f};
        f32x4 acc1 = {0.f, 0.f, 0.f, 0.f};
        #pragma unroll
        for (int i = 0; i < 14; i++) {
            int off = 2 * i + (quad >> 1);
            int idx = off < 27 ? off : 28;
            int j0 = jj[wv][m][idx];      j0 = (off < 27) ? j0 : NN;
            int j1 = jj[wv][m + 16][idx]; j1 = (off < 27) ? j1 : NN;
            bf16x8 a0 = *(const bf16x8*)(fb + (size_t)j0 * 16 + coff);
            bf16x8 a1 = *(const bf16x8*)(fb + (size_t)j1 * 16 + coff);
            acc0 = __builtin_amdgcn_mfma_f32_16x16x32_bf16(a0, bfr[i], acc0, 0, 0, 0);
            acc1 = __builtin_amdgcn_mfma_f32_16x16x32_bf16(a1, bfr[i], acc1, 0, 0, 0);
        }

        // ---- epilogue: D[row=quad*4+r][ch=m], both halves ----
        #pragma unroll
        for (int h = 0; h < 2; h++) {
            int rbase = r0 + (h << 4);
            #pragma unroll
            for (int r4 = 0; r4 < 4; r4++) {
                int row = (quad << 2) + r4;
                float tval = (h ? acc1[r4] : acc0[r4]) * rrl[wv][(h << 4) + row];
                psum += tval; psq += tval * tval;
                int Rr = rbase + row;
                if (Rr < cnt)
                    outbuf[((size_t)b * NN + Rr) * 16 + m] = f2bf(tval);
            }
        }
    }

    // ---- BN partial stats: block reduce, striped atomics ----
    psum += __shfl_xor(psum, 16, 64); psum += __shfl_xor(psum, 32, 64);
    psq  += __shfl_xor(psq, 16, 64);  psq  += __shfl_xor(psq, 32, 64);
    if (lane < 16) { red[wv][lane] = psum; red[wv][16 + lane] = psq; }
    __syncthreads();
    if (threadIdx.x < 32) {
        float v = red[0][threadIdx.x] + red[1][threadIdx.x] +
                  red[2][threadIdx.x] + red[3][threadIdx.x];
        atomicAdd(&stats[(blockIdx.x & 15) * 32 + threadIdx.x], v);
    }
}

// ---------------------------------------------------------------------------
// shared helper: derive per-channel scale/bias from striped stats into LDS
// ---------------------------------------------------------------------------
__device__ __forceinline__ void compute_sb(
    const float* __restrict__ stats, const int* __restrict__ nvv,
    const float* __restrict__ gamma, const float* __restrict__ beta,
    float* sbs /*LDS[32]*/, float* sums /*LDS[32]*/)
{
    int tid = threadIdx.x;
    if (tid < 32) {
        float v = 0.f;
        #pragma unroll
        for (int s = 0; s < 16; s++) v += stats[s * 32 + tid];
        sums[tid] = v;
    }
    __syncthreads();
    if (tid < 16) {
        float cnt = 0.f;
        #pragma unroll
        for (int b = 0; b < NB; b++) cnt += (float)nvv[b];
        float mean = sums[tid] / cnt;
        float var  = fmaxf(sums[16 + tid] / cnt - mean * mean, 0.f);
        float scv = gamma[tid] * rsqrtf(var + EPSC);
        sbs[tid]      = scv;
        sbs[16 + tid] = beta[tid] - mean * scv;
    }
    __syncthreads();
}

// ---------------------------------------------------------------------------
// K6: BN1+ReLU on sorted bf16 -> sorted bf16 (rows [cnt,NN] zeroed); sb fused
// ---------------------------------------------------------------------------
__global__ __launch_bounds__(256) void bnrelu_sorted_kernel(
    const unsigned short* __restrict__ in, const float* __restrict__ stats,
    const int* __restrict__ nvv,
    const float* __restrict__ gamma, const float* __restrict__ beta,
    unsigned short* __restrict__ outb)
{
    __shared__ float sbs[32];
    __shared__ float sums[32];
    compute_sb(stats, nvv, gamma, beta, sbs, sums);

    int b = blockIdx.y;
    int r = blockIdx.x * 256 + threadIdx.x;
    if (r > NN) return;
    int cnt = nvv[b];
    uint4 lo = make_uint4(0, 0, 0, 0), hi = lo;
    if (r < cnt) {
        const uint4* ip = (const uint4*)(in + ((size_t)b * NN + r) * 16);
        uint4 xl = ip[0], xh = ip[1];
        float y[16];
        #pragma unroll
        for (int c = 0; c < 16; c++) {
            unsigned u = (c < 8) ? ((const unsigned*)&xl)[c >> 1]
                                 : ((const unsigned*)&xh)[(c - 8) >> 1];
            unsigned short sv = (c & 1) ? (unsigned short)(u >> 16)
                                        : (unsigned short)(u & 0xffff);
            y[c] = fmaxf(fmaf(bf2f(sv), sbs[c], sbs[16 + c]), 0.f);
        }
        lo = make_uint4(pk2(y[0], y[1]), pk2(y[2], y[3]), pk2(y[4], y[5]), pk2(y[6], y[7]));
        hi = make_uint4(pk2(y[8], y[9]), pk2(y[10], y[11]), pk2(y[12], y[13]), pk2(y[14], y[15]));
    }
    unsigned short* op = outb + ((size_t)b * NS + r) * 16;
    *(uint4*)op       = lo;
    *(uint4*)(op + 8) = hi;
}

// ---------------------------------------------------------------------------
// K8: final BN2+ReLU; scatter valid sorted rows to original order, zero rest
// ---------------------------------------------------------------------------
__global__ __launch_bounds__(256) void final_scatter_kernel(
    const unsigned short* __restrict__ in,     // (B,NN,16) bf16 pre-BN sorted
    const int2* __restrict__ srow,
    const float* __restrict__ stats, const int* __restrict__ nvv,
    const float* __restrict__ gamma, const float* __restrict__ beta,
    float* __restrict__ out)
{
    __shared__ float sbs[32];
    __shared__ float sums[32];
    compute_sb(stats, nvv, gamma, beta, sbs, sums);

    int b = blockIdx.y;
    int r = blockIdx.x * 256 + threadIdx.x;
    int cnt = nvv[b];
    if (r < cnt) {
        const uint4* ip = (const uint4*)(in + ((size_t)b * NN + r) * 16);
        uint4 xl = ip[0], xh = ip[1];
        float y[16];
        #pragma unroll
        for (int c = 0; c < 16; c++) {
            unsigned u = (c < 8) ? ((const unsigned*)&xl)[c >> 1]
                                 : ((const unsigned*)&xh)[(c - 8) >> 1];
            unsigned short sv = (c & 1) ? (unsigned short)(u >> 16)
                                        : (unsigned short)(u & 0xffff);
            y[c] = fmaxf(fmaf(bf2f(sv), sbs[c], sbs[16 + c]), 0.f);
        }
        int n = srow[(size_t)b * NN + r].y;
        float4* op = (float4*)(out + ((size_t)b * NN + n) * 16);
        op[0] = make_float4(y[0],  y[1],  y[2],  y[3]);
        op[1] = make_float4(y[4],  y[5],  y[6],  y[7]);
        op[2] = make_float4(y[8],  y[9],  y[10], y[11]);
        op[3] = make_float4(y[12], y[13], y[14], y[15]);
    } else {
        float4 z = make_float4(0.f, 0.f, 0.f, 0.f);
        float4* op = (float4*)(out + ((size_t)b * NN + r) * 16);
        op[0] = z; op[1] = z; op[2] = z; op[3] = z;
    }
}

// ---------------------------------------------------------------------------
extern "C" void kernel_launch(void* const* d_in, const int* in_sizes, int n_in,
                              void* d_out, int out_size, void* d_ws, size_t ws_size,
                              hipStream_t stream)
{
    const float* feats  = (const float*)d_in[0];
    const int*   xyz    = (const int*)d_in[1];
    const int*   nvv    = (const int*)d_in[2];
    const float* w0     = (const float*)d_in[3];
    const float* w1     = (const float*)d_in[4];
    const float* nw0    = (const float*)d_in[5];
    const float* nw1    = (const float*)d_in[6];
    const float* gamma0 = (const float*)d_in[7];
    const float* beta0  = (const float*)d_in[8];
    const float* gamma1 = (const float*)d_in[9];
    const float* beta1  = (const float*)d_in[10];
    float* out = (float*)d_out;

    char* ws = (char*)d_ws;
    uint32_t* mask    = (uint32_t*)ws;       ws += (size_t)NB * NW * 4;        // 256 KB (memset 0)
    float*    stats1  = (float*)ws;          ws += 16 * 32 * 4;                // 2 KB (memset 0)
    float*    stats2  = (float*)ws;          ws += 16 * 32 * 4;                // 2 KB (memset 0)
    int2*     mwb     = (int2*)ws;           ws += (size_t)NB * NW * 8;        // 512 KB
    int2*     srow    = (int2*)ws;           ws += (size_t)NB * NN * 8;        // 4 MB
    unsigned short* sfA = (unsigned short*)ws; ws += (size_t)NB * NS * 16 * 2; // 16.8 MB
    unsigned short* sfB = (unsigned short*)ws; ws += (size_t)NB * NS * 16 * 2; // 16.8 MB
    unsigned short* bufPre = (unsigned short*)ws; ws += (size_t)NB * NN * 16 * 2; // 16 MB
    unsigned short* wfr = (unsigned short*)ws; ws += (size_t)2 * 14 * 512 * 2; // 28 KB

    // zero mask + both striped stats accumulators in one memset
    hipMemsetAsync(mask, 0, (size_t)NB * NW * 4 + 16 * 32 * 4 * 2, stream);

    dim3 gridBN(NN / 256, NB);
    build_mask_kernel<<<gridBN, 256, 0, stream>>>(xyz, nvv, mask);
    scan_mask_kernel<<<NB, 256, 0, stream>>>(mask, mwb);
    wfrag_kernel<<<2, 256, 0, stream>>>(w0, w1, wfr);
    perm_gather_kernel<<<gridBN, 256, 0, stream>>>(xyz, nvv, mwb, feats, srow, sfA);

    // Layer 1: sorted bf16 in -> sorted bf16 (pre-BN) out + stats1
    conv_mfma_kernel<<<NBLKC, 256, 0, stream>>>(
        sfA, srow, nvv, mwb, wfr, nw0, bufPre, stats1);
    bnrelu_sorted_kernel<<<dim3(NN / 256 + 1, NB), 256, 0, stream>>>(
        bufPre, stats1, nvv, gamma0, beta0, sfB);

    // Layer 2: sorted bf16 in -> sorted bf16 (pre-BN) out + stats2
    conv_mfma_kernel<<<NBLKC, 256, 0, stream>>>(
        sfB, srow, nvv, mwb, wfr + 14 * 512, nw1, bufPre, stats2);

    // Final: BN2+ReLU, scatter to original order, zero invalid rows
    final_scatter_kernel<<<dim3(NN / 256, NB), 256, 0, stream>>>(
        bufPre, srow, stats2, nvv, gamma1, beta1, out);
}

// Round 6
// 240.581 us; speedup vs baseline: 2.5106x; 1.2456x over previous
//
#include <hip/hip_runtime.h>
#include <cstdint>
#include <cstddef>

#define NB 8
#define NN 65536
#define NS (NN + 16)         // sorted-buffer row stride (row NN = zero sentinel)
#define GG 64
#define GG3 (GG*GG*GG)
#define NW (GG3/32)          // 8192 mask words per batch
#define NBLKC 1024           // conv blocks (fully resident: 4/CU)
#define NP32 (NB * 2048)     // 32-voxel tile-pairs total
#define EPSC 1e-3f

typedef __bf16 bf16x8 __attribute__((ext_vector_type(8)));
typedef float  f32x4  __attribute__((ext_vector_type(4)));

__device__ __forceinline__ unsigned short f2bf(float f) {
    unsigned u = __builtin_bit_cast(unsigned, f);
    unsigned r = (u + 0x7fffu + ((u >> 16) & 1u)) >> 16;
    return (unsigned short)r;
}
__device__ __forceinline__ unsigned pk2(float a, float b) {
    return (unsigned)f2bf(a) | ((unsigned)f2bf(b) << 16);
}
__device__ __forceinline__ float bf2f(unsigned short s) {
    return __builtin_bit_cast(float, (unsigned)s << 16);
}

__device__ __forceinline__ int site_rank2(const int2* __restrict__ mwb, int lin) {
    int2 mw = mwb[lin >> 5];
    uint32_t w = (uint32_t)mw.x;
    uint32_t bit = 1u << (lin & 31);
    if (!(w & bit)) return -1;
    return mw.y + __popc(w & (bit - 1u));
}

// ---------------------------------------------------------------------------
// K1: occupancy bitmask (mask pre-memset 0) + weight-fragment packing fused.
// wf[s][i][lane][j] = w_s[off=2i+(quad>>1)][c=(quad&1)*8+j][n=lane&15]
// ---------------------------------------------------------------------------
__global__ __launch_bounds__(256) void build_mask_kernel(
    const int* __restrict__ xyz, const int* __restrict__ nvv,
    uint32_t* __restrict__ mask,
    const float* __restrict__ w0, const float* __restrict__ w1,
    unsigned short* __restrict__ wf)
{
    int b = blockIdx.y;
    int n = blockIdx.x * 256 + threadIdx.x;
    if (n < nvv[b]) {
        const int* cp = xyz + ((size_t)b * NN + n) * 3;
        int lin = cp[0] * (GG * GG) + cp[1] * GG + cp[2];
        atomicOr(&mask[b * NW + (lin >> 5)], 1u << (lin & 31));
    }
    // fused weight packing on blocks (x==0, y<2)
    if (blockIdx.x == 0 && b < 2) {
        const float* w = b ? w1 : w0;
        unsigned short* o = wf + b * 14 * 512;
        for (int idx = threadIdx.x; idx < 14 * 512; idx += 256) {
            int i = idx >> 9;
            int rem = idx & 511;
            int L = rem >> 3, j = rem & 7;
            int quad = L >> 4, nn = L & 15;
            int off = 2 * i + (quad >> 1);
            int c = ((quad & 1) << 3) + j;
            float v = (off < 27) ? w[(off * 16 + c) * 16 + nn] : 0.f;
            o[idx] = f2bf(v);
        }
    }
}

// ---------------------------------------------------------------------------
// K2: exclusive prefix sum of popcounts -> combined int2 {mask_word, base}
// ---------------------------------------------------------------------------
__global__ __launch_bounds__(256) void scan_mask_kernel(
    const uint32_t* __restrict__ mask, int2* __restrict__ mwb)
{
    int b = blockIdx.x;
    const uint32_t* mb = mask + (size_t)b * NW;
    int2* wb = mwb + (size_t)b * NW;
    int t = threadIdx.x;

    uint32_t wv[32];
    int cnts[32];
    int local = 0;
    #pragma unroll
    for (int i = 0; i < 32; i++) {
        wv[i] = mb[t * 32 + i];
        cnts[i] = __popc(wv[i]);
        local += cnts[i];
    }

    __shared__ int sc[256];
    sc[t] = local;
    __syncthreads();
    for (int off = 1; off < 256; off <<= 1) {
        int v = (t >= off) ? sc[t - off] : 0;
        __syncthreads();
        sc[t] += v;
        __syncthreads();
    }
    int base = sc[t] - local;   // exclusive
    #pragma unroll
    for (int i = 0; i < 32; i++) {
        wb[t * 32 + i] = make_int2((int)wv[i], base);
        base += cnts[i];
    }
}

// ---------------------------------------------------------------------------
// K3: permutation + gather feats (fp32) into rank-sorted bf16 rows.
// srow[r] = {lin, original n}. Rows [cnt, NN] zeroed (row NN = sentinel).
// ---------------------------------------------------------------------------
__global__ __launch_bounds__(256) void perm_gather_kernel(
    const int* __restrict__ xyz, const int* __restrict__ nvv,
    const int2* __restrict__ mwb,
    const float* __restrict__ feats,
    int2* __restrict__ srow,
    unsigned short* __restrict__ sfeats)
{
    int b = blockIdx.y;
    int n = blockIdx.x * 256 + threadIdx.x;
    int cnt = nvv[b];
    unsigned short* sfb = sfeats + (size_t)b * NS * 16;
    if (blockIdx.x == 0 && threadIdx.x < 16)
        sfb[(size_t)NN * 16 + threadIdx.x] = 0;     // sentinel row
    if (n < cnt) {
        const int* cp = xyz + ((size_t)b * NN + n) * 3;
        int lin = cp[0] * (GG * GG) + cp[1] * GG + cp[2];
        int r = site_rank2(mwb + (size_t)b * NW, lin);
        srow[(size_t)b * NN + r] = make_int2(lin, n);
        const float4* fp = (const float4*)(feats + ((size_t)b * NN + n) * 16);
        float4 f0 = fp[0], f1 = fp[1], f2 = fp[2], f3 = fp[3];
        uint4 lo = make_uint4(pk2(f0.x, f0.y), pk2(f0.z, f0.w),
                              pk2(f1.x, f1.y), pk2(f1.z, f1.w));
        uint4 hi = make_uint4(pk2(f2.x, f2.y), pk2(f2.z, f2.w),
                              pk2(f3.x, f3.y), pk2(f3.z, f3.w));
        *(uint4*)(sfb + (size_t)r * 16)     = lo;
        *(uint4*)(sfb + (size_t)r * 16 + 8) = hi;
    } else {
        uint4 z = make_uint4(0, 0, 0, 0);
        *(uint4*)(sfb + (size_t)n * 16)     = z;
        *(uint4*)(sfb + (size_t)n * 16 + 8) = z;
    }
}

// ---------------------------------------------------------------------------
// K4/K6: MFMA sparse conv, pair-of-tiles (32 ranks) per wave iteration.
// Rank phase: one mask gather per (voxel, 3x3 column); 3 dz ranks derived
// from one word (+rare predicated 2nd word at z%32 boundaries).
// Output: sorted bf16 pre-BN rows. BN stats via 16-way striped atomics.
// ---------------------------------------------------------------------------
__global__ __launch_bounds__(256, 4) void conv_mfma_kernel(
    const unsigned short* __restrict__ sfeats,  // (B,NS,16) bf16 rank-sorted
    const int2*     __restrict__ srow,          // (B,NN) rank -> {lin, n}
    const int*      __restrict__ nvv,
    const int2*     __restrict__ mwb,           // (B,NW) {mask word, base}
    const unsigned short* __restrict__ wfrag,   // 14*512 bf16 B-frags
    const float*    __restrict__ nw,            // (27,)
    unsigned short* __restrict__ outbuf,        // (B,NN,16) bf16 pre-BN sorted
    float*          __restrict__ stats)         // [16][32] striped accumulators
{
    int lane = threadIdx.x & 63;
    int wv = threadIdx.x >> 6;
    int m = lane & 15, quad = lane >> 4;       // compute-phase layout
    int v = lane & 31, h = lane >> 5;          // rank-phase layout
    int wid = blockIdx.x * 4 + wv;             // flat wave id [0, 4096)

    __shared__ int   jj[4][32][29];            // stride 29: conflict-free-ish
    __shared__ float rrl[4][32];
    __shared__ float red[4][32];
    __shared__ float lnw[27];

    if (threadIdx.x < 27) lnw[threadIdx.x] = nw[threadIdx.x];

    // B-fragments: loaded once per wave, held in registers
    bf16x8 bfr[14];
    #pragma unroll
    for (int i = 0; i < 14; i++)
        bfr[i] = *(const bf16x8*)(wfrag + i * 512 + lane * 8);
    __syncthreads();

    float psum = 0.f, psq = 0.f;
    int coff = (quad & 1) << 3;

    for (int pb = wid; pb < NP32; pb += 4096) {
        int b = pb >> 11;                  // 2048 pair-tiles per batch
        int r0 = (pb & 2047) << 5;         // 32 ranks per pair
        int cnt = nvv[b];
        if (r0 >= cnt) continue;

        const int2* mb = mwb + (size_t)b * NW;
        const unsigned short* fb = sfeats + (size_t)b * NS * 16;
        const int2* sr = srow + (size_t)b * NN;

        // ---- rank phase: slot = (voxel v, column c = 2t + h), c in [0,9) ----
        int Rv = r0 + v;
        bool vld = Rv < cnt;
        int lin = vld ? sr[Rv].x : 0;
        int x = lin >> 12, y = (lin >> 6) & 63, z = lin & 63;
        int zb = z & 31;
        float nc = 0.f;
        #pragma unroll
        for (int t = 0; t < 5; t++) {
            int c = 2 * t + h;
            bool cok = c < 9;
            int cc = cok ? c : 0;
            int dx = cc / 3 - 1, dy = cc % 3 - 1;
            int nx = x + dx, ny = y + dy;
            bool colok = cok & ((unsigned)nx < 64u) & ((unsigned)ny < 64u);
            int wdi = colok ? (((nx << 12) + (ny << 6) + z) >> 5) : 0;

            int2 mw = make_int2(0, 0);
            if (vld & colok) mw = mb[wdi];
            // rare 2nd word when z-1/z+1 crosses the 32-bit boundary
            bool need2 = vld & colok & (((zb == 0) & (z > 0)) | ((zb == 31) & (z < 63)));
            int w2 = wdi + ((zb == 0) ? -1 : 1);
            int2 mw2 = make_int2(0, 0);
            if (need2) mw2 = mb[w2];

            #pragma unroll
            for (int dz = -1; dz <= 1; dz++) {
                int zz = z + dz;
                bool zok = (unsigned)zz < 64u;
                bool same = (dz == 0) | ((dz < 0) ? (zb != 0) : (zb != 31));
                int2 word = same ? mw : mw2;
                int bb = zz & 31;
                uint32_t wm = (uint32_t)word.x;
                bool hit = vld & colok & zok & ((wm >> bb) & 1u);
                int rnk = word.y + __popc(wm & ((1u << bb) - 1u));
                int off = cc * 3 + dz + 1;
                int jv = hit ? rnk : NN;
                if (cok) {
                    jj[wv][v][off] = jv;
                    nc += hit ? lnw[off] : 0.f;
                }
            }
        }
        nc += __shfl_xor(nc, 32, 64);
        if (lane < 32) rrl[wv][v] = 1.f / (1.f + fabsf(nc));

        // ---- compute phase: 28 gathers + 28 MFMAs (two independent chains) ----
        f32x4 acc0 = {0.f, 0.f, 0.f, 0.f};
        f32x4 acc1 = {0.f, 0.f, 0.f, 0.f};
        #pragma unroll
        for (int i = 0; i < 14; i++) {
            int off = 2 * i + (quad >> 1);
            int idx = off < 27 ? off : 28;
            int j0 = jj[wv][m][idx];      j0 = (off < 27) ? j0 : NN;
            int j1 = jj[wv][m + 16][idx]; j1 = (off < 27) ? j1 : NN;
            bf16x8 a0 = *(const bf16x8*)(fb + (size_t)j0 * 16 + coff);
            bf16x8 a1 = *(const bf16x8*)(fb + (size_t)j1 * 16 + coff);
            acc0 = __builtin_amdgcn_mfma_f32_16x16x32_bf16(a0, bfr[i], acc0, 0, 0, 0);
            acc1 = __builtin_amdgcn_mfma_f32_16x16x32_bf16(a1, bfr[i], acc1, 0, 0, 0);
        }

        // ---- epilogue: D[row=quad*4+r][ch=m], both halves ----
        #pragma unroll
        for (int hh = 0; hh < 2; hh++) {
            int rbase = r0 + (hh << 4);
            #pragma unroll
            for (int r4 = 0; r4 < 4; r4++) {
                int row = (quad << 2) + r4;
                float tval = (hh ? acc1[r4] : acc0[r4]) * rrl[wv][(hh << 4) + row];
                psum += tval; psq += tval * tval;
                int Rr = rbase + row;
                if (Rr < cnt)
                    outbuf[((size_t)b * NN + Rr) * 16 + m] = f2bf(tval);
            }
        }
    }

    // ---- BN partial stats: block reduce, striped atomics ----
    psum += __shfl_xor(psum, 16, 64); psum += __shfl_xor(psum, 32, 64);
    psq  += __shfl_xor(psq, 16, 64);  psq  += __shfl_xor(psq, 32, 64);
    if (lane < 16) { red[wv][lane] = psum; red[wv][16 + lane] = psq; }
    __syncthreads();
    if (threadIdx.x < 32) {
        float vv = red[0][threadIdx.x] + red[1][threadIdx.x] +
                   red[2][threadIdx.x] + red[3][threadIdx.x];
        atomicAdd(&stats[(blockIdx.x & 15) * 32 + threadIdx.x], vv);
    }
}

// ---------------------------------------------------------------------------
// shared helper: derive per-channel scale/bias from striped stats into LDS
// ---------------------------------------------------------------------------
__device__ __forceinline__ void compute_sb(
    const float* __restrict__ stats, const int* __restrict__ nvv,
    const float* __restrict__ gamma, const float* __restrict__ beta,
    float* sbs /*LDS[32]*/, float* sums /*LDS[32]*/)
{
    int tid = threadIdx.x;
    if (tid < 32) {
        float v = 0.f;
        #pragma unroll
        for (int s = 0; s < 16; s++) v += stats[s * 32 + tid];
        sums[tid] = v;
    }
    __syncthreads();
    if (tid < 16) {
        float cnt = 0.f;
        #pragma unroll
        for (int b = 0; b < NB; b++) cnt += (float)nvv[b];
        float mean = sums[tid] / cnt;
        float var  = fmaxf(sums[16 + tid] / cnt - mean * mean, 0.f);
        float scv = gamma[tid] * rsqrtf(var + EPSC);
        sbs[tid]      = scv;
        sbs[16 + tid] = beta[tid] - mean * scv;
    }
    __syncthreads();
}

// ---------------------------------------------------------------------------
// K5: BN1+ReLU on sorted bf16 -> sorted bf16 (rows [cnt,NN] zeroed); sb fused
// ---------------------------------------------------------------------------
__global__ __launch_bounds__(256) void bnrelu_sorted_kernel(
    const unsigned short* __restrict__ in, const float* __restrict__ stats,
    const int* __restrict__ nvv,
    const float* __restrict__ gamma, const float* __restrict__ beta,
    unsigned short* __restrict__ outb)
{
    __shared__ float sbs[32];
    __shared__ float sums[32];
    compute_sb(stats, nvv, gamma, beta, sbs, sums);

    int b = blockIdx.y;
    int r = blockIdx.x * 256 + threadIdx.x;
    if (r > NN) return;
    int cnt = nvv[b];
    uint4 lo = make_uint4(0, 0, 0, 0), hi = lo;
    if (r < cnt) {
        const uint4* ip = (const uint4*)(in + ((size_t)b * NN + r) * 16);
        uint4 xl = ip[0], xh = ip[1];
        float y[16];
        #pragma unroll
        for (int c = 0; c < 16; c++) {
            unsigned u = (c < 8) ? ((const unsigned*)&xl)[c >> 1]
                                 : ((const unsigned*)&xh)[(c - 8) >> 1];
            unsigned short sv = (c & 1) ? (unsigned short)(u >> 16)
                                        : (unsigned short)(u & 0xffff);
            y[c] = fmaxf(fmaf(bf2f(sv), sbs[c], sbs[16 + c]), 0.f);
        }
        lo = make_uint4(pk2(y[0], y[1]), pk2(y[2], y[3]), pk2(y[4], y[5]), pk2(y[6], y[7]));
        hi = make_uint4(pk2(y[8], y[9]), pk2(y[10], y[11]), pk2(y[12], y[13]), pk2(y[14], y[15]));
    }
    unsigned short* op = outb + ((size_t)b * NS + r) * 16;
    *(uint4*)op       = lo;
    *(uint4*)(op + 8) = hi;
}

// ---------------------------------------------------------------------------
// K7: final BN2+ReLU; scatter valid sorted rows to original order, zero rest
// ---------------------------------------------------------------------------
__global__ __launch_bounds__(256) void final_scatter_kernel(
    const unsigned short* __restrict__ in,     // (B,NN,16) bf16 pre-BN sorted
    const int2* __restrict__ srow,
    const float* __restrict__ stats, const int* __restrict__ nvv,
    const float* __restrict__ gamma, const float* __restrict__ beta,
    float* __restrict__ out)
{
    __shared__ float sbs[32];
    __shared__ float sums[32];
    compute_sb(stats, nvv, gamma, beta, sbs, sums);

    int b = blockIdx.y;
    int r = blockIdx.x * 256 + threadIdx.x;
    int cnt = nvv[b];
    if (r < cnt) {
        const uint4* ip = (const uint4*)(in + ((size_t)b * NN + r) * 16);
        uint4 xl = ip[0], xh = ip[1];
        float y[16];
        #pragma unroll
        for (int c = 0; c < 16; c++) {
            unsigned u = (c < 8) ? ((const unsigned*)&xl)[c >> 1]
                                 : ((const unsigned*)&xh)[(c - 8) >> 1];
            unsigned short sv = (c & 1) ? (unsigned short)(u >> 16)
                                        : (unsigned short)(u & 0xffff);
            y[c] = fmaxf(fmaf(bf2f(sv), sbs[c], sbs[16 + c]), 0.f);
        }
        int n = srow[(size_t)b * NN + r].y;
        float4* op = (float4*)(out + ((size_t)b * NN + n) * 16);
        op[0] = make_float4(y[0],  y[1],  y[2],  y[3]);
        op[1] = make_float4(y[4],  y[5],  y[6],  y[7]);
        op[2] = make_float4(y[8],  y[9],  y[10], y[11]);
        op[3] = make_float4(y[12], y[13], y[14], y[15]);
    } else {
        float4 z = make_float4(0.f, 0.f, 0.f, 0.f);
        float4* op = (float4*)(out + ((size_t)b * NN + r) * 16);
        op[0] = z; op[1] = z; op[2] = z; op[3] = z;
    }
}

// ---------------------------------------------------------------------------
extern "C" void kernel_launch(void* const* d_in, const int* in_sizes, int n_in,
                              void* d_out, int out_size, void* d_ws, size_t ws_size,
                              hipStream_t stream)
{
    const float* feats  = (const float*)d_in[0];
    const int*   xyz    = (const int*)d_in[1];
    const int*   nvv    = (const int*)d_in[2];
    const float* w0     = (const float*)d_in[3];
    const float* w1     = (const float*)d_in[4];
    const float* nw0    = (const float*)d_in[5];
    const float* nw1    = (const float*)d_in[6];
    const float* gamma0 = (const float*)d_in[7];
    const float* beta0  = (const float*)d_in[8];
    const float* gamma1 = (const float*)d_in[9];
    const float* beta1  = (const float*)d_in[10];
    float* out = (float*)d_out;

    char* ws = (char*)d_ws;
    uint32_t* mask    = (uint32_t*)ws;       ws += (size_t)NB * NW * 4;        // 256 KB (memset 0)
    float*    stats1  = (float*)ws;          ws += 16 * 32 * 4;                // 2 KB (memset 0)
    float*    stats2  = (float*)ws;          ws += 16 * 32 * 4;                // 2 KB (memset 0)
    int2*     mwb     = (int2*)ws;           ws += (size_t)NB * NW * 8;        // 512 KB
    int2*     srow    = (int2*)ws;           ws += (size_t)NB * NN * 8;        // 4 MB
    unsigned short* sfA = (unsigned short*)ws; ws += (size_t)NB * NS * 16 * 2; // 16.8 MB
    unsigned short* sfB = (unsigned short*)ws; ws += (size_t)NB * NS * 16 * 2; // 16.8 MB
    unsigned short* bufPre = (unsigned short*)ws; ws += (size_t)NB * NN * 16 * 2; // 16 MB
    unsigned short* wfr = (unsigned short*)ws; ws += (size_t)2 * 14 * 512 * 2; // 28 KB

    // zero mask + both striped stats accumulators in one memset
    hipMemsetAsync(mask, 0, (size_t)NB * NW * 4 + 16 * 32 * 4 * 2, stream);

    dim3 gridBN(NN / 256, NB);
    build_mask_kernel<<<gridBN, 256, 0, stream>>>(xyz, nvv, mask, w0, w1, wfr);
    scan_mask_kernel<<<NB, 256, 0, stream>>>(mask, mwb);
    perm_gather_kernel<<<gridBN, 256, 0, stream>>>(xyz, nvv, mwb, feats, srow, sfA);

    // Layer 1: sorted bf16 in -> sorted bf16 (pre-BN) out + stats1
    conv_mfma_kernel<<<NBLKC, 256, 0, stream>>>(
        sfA, srow, nvv, mwb, wfr, nw0, bufPre, stats1);
    bnrelu_sorted_kernel<<<dim3(NN / 256 + 1, NB), 256, 0, stream>>>(
        bufPre, stats1, nvv, gamma0, beta0, sfB);

    // Layer 2: sorted bf16 in -> sorted bf16 (pre-BN) out + stats2
    conv_mfma_kernel<<<NBLKC, 256, 0, stream>>>(
        sfB, srow, nvv, mwb, wfr + 14 * 512, nw1, bufPre, stats2);

    // Final: BN2+ReLU, scatter to original order, zero invalid rows
    final_scatter_kernel<<<dim3(NN / 256, NB), 256, 0, stream>>>(
        bufPre, srow, stats2, nvv, gamma1, beta1, out);
}